// Round 7
// baseline (364.451 us; speedup 1.0000x reference)
//
#include <hip/hip_runtime.h>
#include <cstdint>
#include <cstddef>

#define DEVI __device__ __forceinline__

typedef __attribute__((ext_vector_type(8))) short short8;
typedef __attribute__((ext_vector_type(4))) float f32x4;
typedef __attribute__((ext_vector_type(4))) int i32x4;
typedef __bf16 bf16x8 __attribute__((ext_vector_type(8)));

DEVI float sigf(float x) { return 1.0f / (1.0f + __expf(-x)); }
DEVI float tanh_f(float x) { return 2.0f / (1.0f + __expf(-2.0f * x)) - 1.0f; }

DEVI short f2bf(float x) {
    uint32_t u = __builtin_bit_cast(uint32_t, x);
    u += 0x7FFFu + ((u >> 16) & 1u);   // RTNE
    return (short)(u >> 16);
}
DEVI float bf2f(short s) {
    uint32_t u = ((uint32_t)(unsigned short)s) << 16;
    return __builtin_bit_cast(float, u);
}
DEVI uint32_t cvtpk(float lo, float hi) {   // 2x f32 -> packed bf16 (1 VALU op)
    uint32_t r;
    asm("v_cvt_pk_bf16_f32 %0, %1, %2" : "=v"(r) : "v"(lo), "v"(hi));
    return r;
}

DEVI void gload16(const void* g, void* l) {
    __builtin_amdgcn_global_load_lds(
        (const __attribute__((address_space(1))) void*)g,
        (__attribute__((address_space(3))) void*)l, 16, 0, 0);
}

DEVI f32x4 mfma16(short8 a, short8 b, f32x4 c) {
    return __builtin_amdgcn_mfma_f32_16x16x32_bf16(
        __builtin_bit_cast(bf16x8, a), __builtin_bit_cast(bf16x8, b), c, 0, 0, 0);
}

// ---------------- prep kernels ----------------

// Wstk[n'][k], n' = hblk*64 + gate*16 + hl  (orig gate row = gate*1024 + hblk*16 + hl)
// k: [0,300)=W_ih, k==300 -> b_ih+b_hh (paired with constant-1.0 x column),
//    (300,320)=0, [320,1344)=W_hh
__global__ __launch_bounds__(256) void prep_wstk(const float* __restrict__ Wih,
                                                 const float* __restrict__ Whh,
                                                 const float* __restrict__ bih,
                                                 const float* __restrict__ bhh,
                                                 short* __restrict__ Wstk) {
    int idx = blockIdx.x * 256 + threadIdx.x;
    if (idx >= 4096 * 1344) return;
    int n = idx / 1344, k = idx - n * 1344;
    int hblk = n >> 6, gate = (n >> 4) & 3, hl = n & 15;
    int on = gate * 1024 + hblk * 16 + hl;
    float v = 0.f;
    if (k < 300) v = Wih[on * 300 + k];
    else if (k == 300) v = bih[on] + bhh[on];
    else if (k >= 320) v = Whh[on * 1024 + (k - 320)];
    Wstk[idx] = f2bf(v);
}

// x_bf16[t][b][e], e in [0,320): e<300 -> q, e==300 -> 1.0 (bias), else 0.
__global__ __launch_bounds__(256) void prep_x(const float* __restrict__ q,
                                              short* __restrict__ xb) {
    int idx = blockIdx.x * 256 + threadIdx.x;
    if (idx >= 14 * 256 * 320) return;
    int t = idx / (256 * 320);
    int r = idx - t * 256 * 320;
    int b = r / 320, e = r - b * 320;
    float v = (e < 300) ? q[(b * 14 + t) * 300 + e] : (e == 300 ? 1.0f : 0.0f);
    xb[idx] = f2bf(v);
}

// Wcat[n'][k], n' in [0,1024): hg=n'>>5, which=(n'>>4)&1, h=hg*16+(n'&15).
__global__ __launch_bounds__(256) void prep_wcat(const float* __restrict__ Ww,
                                                 const float* __restrict__ Wpw,
                                                 short* __restrict__ Wcat) {
    int idx = blockIdx.x * 256 + threadIdx.x;
    if (idx >= 1024 * 3072) return;
    int n = idx / 3072, k = idx - n * 3072;
    int hg = n >> 5, which = (n >> 4) & 1, hl = n & 15;
    int h = hg * 16 + hl;
    const float* src = which ? Wpw : Ww;
    Wcat[idx] = f2bf(src[h * 3072 + k]);
}

// exclusive prefix sum of index[256] -> cum[0..256]; cum[256]=Mlive.
// Also builds rowmap[dr]/bmap[dr] for dr < Mlive + 128 pad entries -> row 0.
__global__ __launch_bounds__(256) void prep_index(const int* __restrict__ index,
                                                  int* __restrict__ cum,
                                                  int* __restrict__ rowmap,
                                                  int* __restrict__ bmap) {
    __shared__ int s[256];
    int t = threadIdx.x;
    int myidx = index[t];
    s[t] = myidx;
    __syncthreads();
    for (int off = 1; off < 256; off <<= 1) {
        int v = (t >= off) ? s[t - off] : 0;
        __syncthreads();
        s[t] += v;
        __syncthreads();
    }
    cum[t + 1] = s[t];
    if (t == 0) cum[0] = 0;
    int base = s[t] - myidx;
    for (int j = 0; j < myidx; ++j) {
        rowmap[base + j] = t * 100 + j;
        bmap[base + j] = t;
    }
    int Ml = s[255];
    if (t < 128) { rowmap[Ml + t] = 0; bmap[Ml + t] = 0; }
}

// ---------------- LSTM part 1: x-projection for all timesteps ----------------

// xg[t*256+b][n'] = xb @ Wstk(:, 0:320)^T, bf16 out. M=3584, N=4096, K=320.
__global__ __launch_bounds__(256) void xg_gemm(const short* __restrict__ xb,   // [3584][320]
                                               const short* __restrict__ Wstk, // [4096][1344]
                                               short* __restrict__ xg) {       // [3584][4096]
    __shared__ __attribute__((aligned(16))) short As[128 * 64];
    __shared__ __attribute__((aligned(16))) short Bs[128 * 64];
    const int tid = threadIdx.x, l = tid & 63, w = tid >> 6;
    const int n0 = blockIdx.x * 128;  // 32
    const int m0 = blockIdx.y * 128;  // 28
    const int wm = w >> 1, wn = w & 1;

    const short* asrc[4];
    const short* bsrc[4];
    for (int i = 0; i < 4; i++) {
        int r = w * 32 + i * 8 + (l >> 3);
        int cs = (l & 7) ^ (r & 7);
        asrc[i] = xb + (size_t)(m0 + r) * 320 + cs * 8;
        bsrc[i] = Wstk + (size_t)(n0 + r) * 1344 + cs * 8;
    }

    f32x4 acc[4][4];
    for (int i = 0; i < 4; i++)
        for (int j = 0; j < 4; j++) acc[i][j] = f32x4{0.f, 0.f, 0.f, 0.f};

    for (int kt = 0; kt < 5; ++kt) {
        const int k0 = kt * 64;
        __syncthreads();
        for (int i = 0; i < 4; i++)
            gload16(asrc[i] + k0, &As[(w * 32 + i * 8) * 64]);
        for (int i = 0; i < 4; i++)
            gload16(bsrc[i] + k0, &Bs[(w * 32 + i * 8) * 64]);
        __syncthreads();
        for (int ks = 0; ks < 2; ++ks) {
            short8 a[4], b[4];
            for (int mf = 0; mf < 4; ++mf) {
                int m = wm * 64 + mf * 16 + (l & 15);
                int ca = (ks * 4 + (l >> 4)) ^ (m & 7);
                a[mf] = *(const short8*)&As[m * 64 + ca * 8];
            }
            for (int nf = 0; nf < 4; ++nf) {
                int n = wn * 64 + nf * 16 + (l & 15);
                int cb = (ks * 4 + (l >> 4)) ^ (n & 7);
                b[nf] = *(const short8*)&Bs[n * 64 + cb * 8];
            }
            for (int mf = 0; mf < 4; ++mf)
                for (int nf = 0; nf < 4; ++nf)
                    acc[mf][nf] = mfma16(a[mf], b[nf], acc[mf][nf]);
        }
    }
    const int hl = l & 15, hi = l >> 4;
    for (int mf = 0; mf < 4; ++mf)
        for (int nf = 0; nf < 4; ++nf)
            for (int rg = 0; rg < 4; ++rg) {
                int row = m0 + wm * 64 + mf * 16 + hi * 4 + rg;
                int col = n0 + wn * 64 + nf * 16 + hl;
                xg[(size_t)row * 4096 + col] = f2bf(acc[mf][nf][rg]);
            }
}

// ---------------- LSTM part 2: per-step recurrent GEMM, dbuf pipelined ----------------

// gates = h_t @ Whh'^T (+ xg[t]); K=1024, BK=128 (8 kt), double-buffered LDS,
// counted vmcnt so prefetch stays in flight across barriers. Tile 32m x 64n',
// 2 waves, grid 512 (2 blocks/CU), XCD-pinned n' panels.
__global__ __launch_bounds__(128) void lstm_step(const short* __restrict__ hin,  // [256][1024]
                                                 const short* __restrict__ Wstk, // [4096][1344]
                                                 const short* __restrict__ xg_t, // [256][4096]
                                                 float* __restrict__ c,          // [256][1024]
                                                 short* __restrict__ hout,
                                                 int dogemm) {
    __shared__ __attribute__((aligned(16))) short As[2][32 * 128];
    __shared__ __attribute__((aligned(16))) short Bs[2][64 * 128];
    const int tid = threadIdx.x, l = tid & 63, w = tid >> 6;
    const int hi = l >> 4, hl = l & 15;
    const int bid = blockIdx.x;             // 512
    const int xcd = bid & 7, ii = bid >> 3;
    const int ny = xcd * 8 + (ii & 7);      // n' panel [0,64)
    const int mx = ii >> 3;                 // m panel [0,8)
    const int m0 = mx * 32, n0g = ny * 64;

    f32x4 acc[4];
    for (int i = 0; i < 4; i++) acc[i] = f32x4{0.f, 0.f, 0.f, 0.f};

    if (dogemm) {
        const short* asrc[4];
        const short* bsrc[8];
        for (int i = 0; i < 4; i++) {
            int s = i * 128 + tid;
            int r = s >> 4, cs = s & 15;
            asrc[i] = hin + (size_t)(m0 + r) * 1024 + ((cs ^ (r & 15)) * 8);
        }
        for (int i = 0; i < 8; i++) {
            int s = i * 128 + tid;
            int r = s >> 4, cs = s & 15;
            bsrc[i] = Wstk + (size_t)(n0g + r) * 1344 + 320 + ((cs ^ (r & 15)) * 8);
        }
        // prologue: stage kt=0 into buf 0
        for (int i = 0; i < 4; i++) gload16(asrc[i], &As[0][(i * 128 + tid) * 8]);
        for (int i = 0; i < 8; i++) gload16(bsrc[i], &Bs[0][(i * 128 + tid) * 8]);

        for (int kt = 0; kt < 8; ++kt) {
            const int cur = kt & 1;
            if (kt < 7) {
                const int k0 = (kt + 1) * 128;
                for (int i = 0; i < 4; i++)
                    gload16(asrc[i] + k0, &As[cur ^ 1][(i * 128 + tid) * 8]);
                for (int i = 0; i < 8; i++)
                    gload16(bsrc[i] + k0, &Bs[cur ^ 1][(i * 128 + tid) * 8]);
                asm volatile("s_waitcnt vmcnt(12)" ::: "memory");
            } else {
                asm volatile("s_waitcnt vmcnt(0)" ::: "memory");
            }
            __builtin_amdgcn_sched_barrier(0);
            __builtin_amdgcn_s_barrier();
            __builtin_amdgcn_sched_barrier(0);
#pragma unroll
            for (int ks = 0; ks < 4; ++ks) {
                const int mrow = w * 16 + hl;
                const int ca = (ks * 4 + hi) ^ hl;
                short8 a = *(const short8*)&As[cur][mrow * 128 + ca * 8];
#pragma unroll
                for (int nf = 0; nf < 4; ++nf) {
                    const int nrow = nf * 16 + hl;
                    short8 b = *(const short8*)&Bs[cur][nrow * 128 + ca * 8];
                    acc[nf] = mfma16(a, b, acc[nf]);
                }
            }
            __builtin_amdgcn_sched_barrier(0);
            asm volatile("s_waitcnt lgkmcnt(0)" ::: "memory");
            __builtin_amdgcn_s_barrier();
            __builtin_amdgcn_sched_barrier(0);
        }
    }

    // epilogue: acc[gate] + xg -> cell update -> h_{t+1}
    const short* xr0 = xg_t + (size_t)(m0 + w * 16 + hi * 4) * 4096 + n0g + hl;
    for (int rg = 0; rg < 4; ++rg) {
        const short* xr = xr0 + (size_t)rg * 4096;
        float ig = acc[0][rg] + bf2f(xr[0]);
        float fg = acc[1][rg] + bf2f(xr[16]);
        float gg = acc[2][rg] + bf2f(xr[32]);
        float og = acc[3][rg] + bf2f(xr[48]);
        size_t off = (size_t)(m0 + w * 16 + hi * 4 + rg) * 1024 + ny * 16 + hl;
        float cn = sigf(fg) * c[off] + sigf(ig) * tanh_f(gg);
        c[off] = cn;
        hout[off] = f2bf(sigf(og) * tanh_f(cn));
    }
}

// ---------------- gated MLP: fully pipelined staging ----------------

// C[dr][1024]: A row dr = box[rowmap[dr]] (f32 -> bf16 via cvt_pk) ‖ h[bmap[dr]].
// 128x128 tile, BK=64, 4 waves (2x2). ALL staging is one K-step ahead:
//   A (box f32 / h bf16) -> regs at kt-1, ds_write at kt (single-buffer As);
//   B (Wcat)            -> gload16 into double-buffered Bs at kt-1.
// Only counted vmcnt before compute -> no exposed load latency per kt.
__global__ __launch_bounds__(256, 3) void mlp_gemm(const float* __restrict__ box,  // [25600][2048]
                                                   const short* __restrict__ hb,   // [256][1024]
                                                   const short* __restrict__ Wcat, // [1024][3072]
                                                   const int* __restrict__ mliveptr,
                                                   const int* __restrict__ rowmap,
                                                   const int* __restrict__ bmap,
                                                   const float* __restrict__ Wb,
                                                   const float* __restrict__ Wpb,
                                                   const float* __restrict__ fw,
                                                   float* __restrict__ logits) {
    __shared__ __attribute__((aligned(16))) short As[128 * 64];     // 16 KB
    __shared__ __attribute__((aligned(16))) short Bs[2][128 * 64];  // 32 KB
    const int Mlive = *mliveptr;
    const int tid = threadIdx.x, l = tid & 63, w = tid >> 6;
    const int bid = blockIdx.x;              // 1600
    const int xcd = bid & 7, ii = bid >> 3;  // ii in [0,200)
    const int x = ii & 7, q = ii >> 3;       // q in [0,25)
    const int y = q * 8 + xcd;
    const int n0 = x * 128, m0 = y * 128;
    if (m0 >= Mlive) return;
    const int wm = w >> 1, wn = w & 1;

    // A staging: slot = tid + i*256 -> (row r, chunk cc); fixed LDS dest awr[i]
    const float* boxp[4];   // box source (f32), row-indirect
    const short* hpre[4];   // h source (bf16), sample-indirect
    short* awr[4];
    for (int i = 0; i < 4; i++) {
        int slot = tid + i * 256;
        int r = slot >> 3, cc = slot & 7;
        boxp[i] = box + (size_t)rowmap[m0 + r] * 2048 + cc * 8;
        hpre[i] = hb + (size_t)bmap[m0 + r] * 1024 + cc * 8;
        awr[i] = &As[r * 64 + ((cc ^ (r & 7)) * 8)];
    }
    const short* bsrc[4];
    for (int i = 0; i < 4; i++) {
        int r = w * 32 + i * 8 + (l >> 3);
        int cs = (l & 7) ^ (r & 7);
        bsrc[i] = Wcat + (size_t)(n0 + r) * 3072 + cs * 8;
    }

    f32x4 acc[4][4];
    for (int i = 0; i < 4; i++)
        for (int j = 0; j < 4; j++) acc[i][j] = f32x4{0.f, 0.f, 0.f, 0.f};

    // prologue: A(0) -> regs, B(0) -> Bs[0]
    float4 pva[4], pvb[4];
    short8 hreg[4];
    for (int i = 0; i < 4; i++) {
        pva[i] = *(const float4*)(boxp[i]);
        pvb[i] = *(const float4*)(boxp[i] + 4);
    }
    for (int i = 0; i < 4; i++)
        gload16(bsrc[i], &Bs[0][(w * 32 + i * 8) * 64]);

    for (int kt = 0; kt < 48; ++kt) {
        const int cur = kt & 1;
        // barrier_top: all waves finished compute(kt-1) -> As and Bs[cur^1] free
        __builtin_amdgcn_sched_barrier(0);
        __builtin_amdgcn_s_barrier();
        __builtin_amdgcn_sched_barrier(0);
        // write A(kt) from regs into As
        if (kt < 32) {
            for (int i = 0; i < 4; i++) {
                i32x4 d;
                d[0] = (int)cvtpk(pva[i].x, pva[i].y);
                d[1] = (int)cvtpk(pva[i].z, pva[i].w);
                d[2] = (int)cvtpk(pvb[i].x, pvb[i].y);
                d[3] = (int)cvtpk(pvb[i].z, pvb[i].w);
                *(i32x4*)awr[i] = d;
            }
        } else {
            for (int i = 0; i < 4; i++)
                *(short8*)awr[i] = hreg[i];
        }
        // issue B(kt+1) and prefetch A(kt+1)
        if (kt < 47) {
            const int k1 = (kt + 1) * 64;
            for (int i = 0; i < 4; i++)
                gload16(bsrc[i] + k1, &Bs[cur ^ 1][(w * 32 + i * 8) * 64]);
            if (kt + 1 < 32) {
                for (int i = 0; i < 4; i++) {
                    pva[i] = *(const float4*)(boxp[i] + k1);
                    pvb[i] = *(const float4*)(boxp[i] + k1 + 4);
                }
                asm volatile("s_waitcnt vmcnt(12) lgkmcnt(0)" ::: "memory");
            } else {
                const int kq = k1 - 2048;
                for (int i = 0; i < 4; i++)
                    hreg[i] = *(const short8*)(hpre[i] + kq);
                asm volatile("s_waitcnt vmcnt(8) lgkmcnt(0)" ::: "memory");
            }
        } else {
            asm volatile("s_waitcnt vmcnt(0) lgkmcnt(0)" ::: "memory");
        }
        // barrier_bottom: As(kt) visible, Bs[cur] = B(kt) resident
        __builtin_amdgcn_sched_barrier(0);
        __builtin_amdgcn_s_barrier();
        __builtin_amdgcn_sched_barrier(0);
        for (int ks = 0; ks < 2; ++ks) {
            short8 a[4], b[4];
            for (int mf = 0; mf < 4; ++mf) {
                int m = wm * 64 + mf * 16 + (l & 15);
                int ca = (ks * 4 + (l >> 4)) ^ (m & 7);
                a[mf] = *(const short8*)&As[m * 64 + ca * 8];
            }
            for (int nf = 0; nf < 4; ++nf) {
                int n = wn * 64 + nf * 16 + (l & 15);
                int cb = (ks * 4 + (l >> 4)) ^ (n & 7);
                b[nf] = *(const short8*)&Bs[cur][n * 64 + cb * 8];
            }
            for (int mf = 0; mf < 4; ++mf)
                for (int nf = 0; nf < 4; ++nf)
                    acc[mf][nf] = mfma16(a[mf], b[nf], acc[mf][nf]);
        }
    }

    const int hl = l & 15, hi = l >> 4;
    for (int mf = 0; mf < 4; ++mf) {
        float part[4] = {0.f, 0.f, 0.f, 0.f};
        for (int p = 0; p < 2; ++p) {
            int ntg = (n0 + wn * 64) / 16 + 2 * p;
            int hg = ntg >> 1;
            int h = hg * 16 + hl;
            float fwv = fw[h], wbv = Wb[h], wpbv = Wpb[h];
            for (int rg = 0; rg < 4; ++rg) {
                float y2 = tanh_f(acc[mf][2 * p][rg] + wbv);
                float g2 = sigf(acc[mf][2 * p + 1][rg] + wpbv);
                part[rg] += y2 * g2 * fwv;
            }
        }
        for (int rg = 0; rg < 4; ++rg) {
            float v = part[rg];
            v += __shfl_xor(v, 1, 64);
            v += __shfl_xor(v, 2, 64);
            v += __shfl_xor(v, 4, 64);
            v += __shfl_xor(v, 8, 64);
            if (hl == 0) {
                int row = m0 + wm * 64 + mf * 16 + hi * 4 + rg;
                atomicAdd(&logits[row], v);
            }
        }
    }
}

__global__ __launch_bounds__(128) void reduce_out(const float* __restrict__ logits,
                                                  const int* __restrict__ index,
                                                  const int* __restrict__ cum,
                                                  float* __restrict__ out) {
    int b = blockIdx.x, t = threadIdx.x;
    int idx = index[b];
    int base = cum[b];
    float v = 0.f;
    if (t < 100 && t < idx) v = sigf(logits[base + t]);
    for (int m = 32; m; m >>= 1) v += __shfl_down(v, m, 64);
    __shared__ float s[2];
    if ((t & 63) == 0) s[t >> 6] = v;
    __syncthreads();
    if (t == 0) out[b] = s[0] + s[1];
}

// ---------------- host ----------------

extern "C" void kernel_launch(void* const* d_in, const int* in_sizes, int n_in,
                              void* d_out, int out_size, void* d_ws, size_t ws_size,
                              hipStream_t stream) {
    (void)in_sizes; (void)n_in; (void)out_size; (void)ws_size;
    const float* box = (const float*)d_in[2];
    const float* qf  = (const float*)d_in[3];
    const int* index = (const int*)d_in[5];
    const float* Wih = (const float*)d_in[6];
    const float* Whh = (const float*)d_in[7];
    const float* bih = (const float*)d_in[8];
    const float* bhh = (const float*)d_in[9];
    const float* Ww  = (const float*)d_in[10];
    const float* Wb  = (const float*)d_in[11];
    const float* Wpw = (const float*)d_in[12];
    const float* Wpb = (const float*)d_in[13];
    const float* fw  = (const float*)d_in[14];

    char* p = (char*)d_ws;
    short* Wstk = (short*)p;  p += (size_t)4096 * 1344 * 2;
    short* Wcat = (short*)p;  p += (size_t)1024 * 3072 * 2;
    short* xb   = (short*)p;  p += (size_t)3584 * 320 * 2;
    short* hb0  = (short*)p;  p += (size_t)256 * 1024 * 2;
    short* hb1  = (short*)p;  p += (size_t)256 * 1024 * 2;
    short* xg   = (short*)p;  p += (size_t)3584 * 4096 * 2;
    float* c    = (float*)p;  p += (size_t)256 * 1024 * 4;
    int*   cum  = (int*)p;    p += 260 * 4;
    int*   rowmap = (int*)p;  p += (size_t)(25600 + 128) * 4;
    int*   bmap = (int*)p;    p += (size_t)(25600 + 128) * 4;
    float* lgt  = (float*)p;  p += (size_t)25600 * 4;

    hipMemsetAsync(hb0, 0, (size_t)256 * 1024 * 2, stream);
    hipMemsetAsync(c, 0, (size_t)256 * 1024 * 4, stream);
    hipMemsetAsync(lgt, 0, (size_t)25600 * 4, stream);

    prep_index<<<1, 256, 0, stream>>>(index, cum, rowmap, bmap);
    prep_wstk<<<(4096 * 1344) / 256, 256, 0, stream>>>(Wih, Whh, bih, bhh, Wstk);
    prep_x<<<(14 * 256 * 320) / 256, 256, 0, stream>>>(qf, xb);
    prep_wcat<<<(1024 * 3072) / 256, 256, 0, stream>>>(Ww, Wpw, Wcat);

    xg_gemm<<<dim3(32, 28), 256, 0, stream>>>(xb, Wstk, xg);

    short* hbuf[2] = {hb0, hb1};
    for (int t = 0; t < 14; ++t) {
        lstm_step<<<512, 128, 0, stream>>>(
            hbuf[t & 1], Wstk, xg + (size_t)t * 256 * 4096, c,
            hbuf[(t & 1) ^ 1], t == 0 ? 0 : 1);
    }
    // final hidden state h_14 in hb0

    mlp_gemm<<<1600, 256, 0, stream>>>(box, hb0, Wcat, cum + 256, rowmap, bmap,
                                       Wb, Wpb, fw, lgt);
    reduce_out<<<256, 128, 0, stream>>>(lgt, index, cum, (float*)d_out);
}

// Round 8
// 351.743 us; speedup vs baseline: 1.0361x; 1.0361x over previous
//
#include <hip/hip_runtime.h>
#include <cstdint>
#include <cstddef>

#define DEVI __device__ __forceinline__

typedef __attribute__((ext_vector_type(8))) short short8;
typedef __attribute__((ext_vector_type(4))) float f32x4;
typedef __bf16 bf16x8 __attribute__((ext_vector_type(8)));

DEVI float sigf(float x) { return 1.0f / (1.0f + __expf(-x)); }
DEVI float tanh_f(float x) { return 2.0f / (1.0f + __expf(-2.0f * x)) - 1.0f; }

DEVI short f2bf(float x) {
    uint32_t u = __builtin_bit_cast(uint32_t, x);
    u += 0x7FFFu + ((u >> 16) & 1u);   // RTNE
    return (short)(u >> 16);
}
DEVI float bf2f(short s) {
    uint32_t u = ((uint32_t)(unsigned short)s) << 16;
    return __builtin_bit_cast(float, u);
}

DEVI void gload16(const void* g, void* l) {
    __builtin_amdgcn_global_load_lds(
        (const __attribute__((address_space(1))) void*)g,
        (__attribute__((address_space(3))) void*)l, 16, 0, 0);
}

DEVI f32x4 mfma16(short8 a, short8 b, f32x4 c) {
    return __builtin_amdgcn_mfma_f32_16x16x32_bf16(
        __builtin_bit_cast(bf16x8, a), __builtin_bit_cast(bf16x8, b), c, 0, 0, 0);
}

// ---------------- prep kernels ----------------

// Wstk[n'][k], n' = hblk*64 + gate*16 + hl  (orig gate row = gate*1024 + hblk*16 + hl)
// k: [0,300)=W_ih, k==300 -> b_ih+b_hh (paired with constant-1.0 x column),
//    (300,320)=0, [320,1344)=W_hh
__global__ __launch_bounds__(256) void prep_wstk(const float* __restrict__ Wih,
                                                 const float* __restrict__ Whh,
                                                 const float* __restrict__ bih,
                                                 const float* __restrict__ bhh,
                                                 short* __restrict__ Wstk) {
    int idx = blockIdx.x * 256 + threadIdx.x;
    if (idx >= 4096 * 1344) return;
    int n = idx / 1344, k = idx - n * 1344;
    int hblk = n >> 6, gate = (n >> 4) & 3, hl = n & 15;
    int on = gate * 1024 + hblk * 16 + hl;
    float v = 0.f;
    if (k < 300) v = Wih[on * 300 + k];
    else if (k == 300) v = bih[on] + bhh[on];
    else if (k >= 320) v = Whh[on * 1024 + (k - 320)];
    Wstk[idx] = f2bf(v);
}

// x_bf16[t][b][e], e in [0,320): e<300 -> q, e==300 -> 1.0 (bias), else 0.
__global__ __launch_bounds__(256) void prep_x(const float* __restrict__ q,
                                              short* __restrict__ xb) {
    int idx = blockIdx.x * 256 + threadIdx.x;
    if (idx >= 14 * 256 * 320) return;
    int t = idx / (256 * 320);
    int r = idx - t * 256 * 320;
    int b = r / 320, e = r - b * 320;
    float v = (e < 300) ? q[(b * 14 + t) * 300 + e] : (e == 300 ? 1.0f : 0.0f);
    xb[idx] = f2bf(v);
}

// Wcat[n'][k], n' in [0,1024): hg=n'>>5, which=(n'>>4)&1, h=hg*16+(n'&15).
__global__ __launch_bounds__(256) void prep_wcat(const float* __restrict__ Ww,
                                                 const float* __restrict__ Wpw,
                                                 short* __restrict__ Wcat) {
    int idx = blockIdx.x * 256 + threadIdx.x;
    if (idx >= 1024 * 3072) return;
    int n = idx / 3072, k = idx - n * 3072;
    int hg = n >> 5, which = (n >> 4) & 1, hl = n & 15;
    int h = hg * 16 + hl;
    const float* src = which ? Wpw : Ww;
    Wcat[idx] = f2bf(src[h * 3072 + k]);
}

// exclusive prefix sum of index[256] -> cum[0..256]; cum[256]=Mlive.
// rowmap[dr] = original row, bmap[dr] = sample b; +128 pad entries -> row/sample 0.
__global__ __launch_bounds__(256) void prep_index(const int* __restrict__ index,
                                                  int* __restrict__ cum,
                                                  int* __restrict__ rowmap,
                                                  int* __restrict__ bmap) {
    __shared__ int s[256];
    int t = threadIdx.x;
    int myidx = index[t];
    s[t] = myidx;
    __syncthreads();
    for (int off = 1; off < 256; off <<= 1) {
        int v = (t >= off) ? s[t - off] : 0;
        __syncthreads();
        s[t] += v;
        __syncthreads();
    }
    cum[t + 1] = s[t];
    if (t == 0) cum[0] = 0;
    int base = s[t] - myidx;
    for (int j = 0; j < myidx; ++j) {
        rowmap[base + j] = t * 100 + j;
        bmap[base + j] = t;
    }
    int Ml = s[255];
    if (t < 128) { rowmap[Ml + t] = 0; bmap[Ml + t] = 0; }
}

// Compact live box rows into Ac[dr][2048] bf16 (box part only; h read directly
// by mlp_gemm via bmap). One block per original row, early-exit for dead rows.
__global__ __launch_bounds__(256) void compact_box(const float* __restrict__ box,
                                                   const int* __restrict__ index,
                                                   const int* __restrict__ cum,
                                                   short* __restrict__ Ac) {
    int m = blockIdx.x;                  // 25600
    int b = m / 100, j = m - b * 100;
    if (j >= index[b]) return;
    size_t dr = (size_t)(cum[b] + j);
    int t = threadIdx.x;
    const float* src = box + (size_t)m * 2048 + t * 8;
    float4 v0 = *(const float4*)src;
    float4 v1 = *(const float4*)(src + 4);
    short8 s;
    s[0] = f2bf(v0.x); s[1] = f2bf(v0.y); s[2] = f2bf(v0.z); s[3] = f2bf(v0.w);
    s[4] = f2bf(v1.x); s[5] = f2bf(v1.y); s[6] = f2bf(v1.z); s[7] = f2bf(v1.w);
    *(short8*)&Ac[dr * 2048 + t * 8] = s;
}

// ---------------- LSTM part 1: x-projection for all timesteps ----------------

// xg[t*256+b][n'] = xb @ Wstk(:, 0:320)^T, bf16 out. M=3584, N=4096, K=320.
__global__ __launch_bounds__(256) void xg_gemm(const short* __restrict__ xb,   // [3584][320]
                                               const short* __restrict__ Wstk, // [4096][1344]
                                               short* __restrict__ xg) {       // [3584][4096]
    __shared__ __attribute__((aligned(16))) short As[128 * 64];
    __shared__ __attribute__((aligned(16))) short Bs[128 * 64];
    const int tid = threadIdx.x, l = tid & 63, w = tid >> 6;
    const int n0 = blockIdx.x * 128;  // 32
    const int m0 = blockIdx.y * 128;  // 28
    const int wm = w >> 1, wn = w & 1;

    const short* asrc[4];
    const short* bsrc[4];
    for (int i = 0; i < 4; i++) {
        int r = w * 32 + i * 8 + (l >> 3);
        int cs = (l & 7) ^ (r & 7);
        asrc[i] = xb + (size_t)(m0 + r) * 320 + cs * 8;
        bsrc[i] = Wstk + (size_t)(n0 + r) * 1344 + cs * 8;
    }

    f32x4 acc[4][4];
    for (int i = 0; i < 4; i++)
        for (int j = 0; j < 4; j++) acc[i][j] = f32x4{0.f, 0.f, 0.f, 0.f};

    for (int kt = 0; kt < 5; ++kt) {
        const int k0 = kt * 64;
        __syncthreads();
        for (int i = 0; i < 4; i++)
            gload16(asrc[i] + k0, &As[(w * 32 + i * 8) * 64]);
        for (int i = 0; i < 4; i++)
            gload16(bsrc[i] + k0, &Bs[(w * 32 + i * 8) * 64]);
        __syncthreads();
        for (int ks = 0; ks < 2; ++ks) {
            short8 a[4], b[4];
            for (int mf = 0; mf < 4; ++mf) {
                int m = wm * 64 + mf * 16 + (l & 15);
                int ca = (ks * 4 + (l >> 4)) ^ (m & 7);
                a[mf] = *(const short8*)&As[m * 64 + ca * 8];
            }
            for (int nf = 0; nf < 4; ++nf) {
                int n = wn * 64 + nf * 16 + (l & 15);
                int cb = (ks * 4 + (l >> 4)) ^ (n & 7);
                b[nf] = *(const short8*)&Bs[n * 64 + cb * 8];
            }
            for (int mf = 0; mf < 4; ++mf)
                for (int nf = 0; nf < 4; ++nf)
                    acc[mf][nf] = mfma16(a[mf], b[nf], acc[mf][nf]);
        }
    }
    const int hl = l & 15, hi = l >> 4;
    for (int mf = 0; mf < 4; ++mf)
        for (int nf = 0; nf < 4; ++nf)
            for (int rg = 0; rg < 4; ++rg) {
                int row = m0 + wm * 64 + mf * 16 + hi * 4 + rg;
                int col = n0 + wn * 64 + nf * 16 + hl;
                xg[(size_t)row * 4096 + col] = f2bf(acc[mf][nf][rg]);
            }
}

// ---------------- LSTM part 2: per-step recurrent GEMM, dbuf pipelined ----------------

// gates = h_t @ Whh'^T (+ xg[t]); K=1024, BK=128 (8 kt), double-buffered LDS,
// counted vmcnt so prefetch stays in flight across barriers. Tile 32m x 64n',
// 2 waves, grid 512 (2 blocks/CU), XCD-pinned n' panels.
__global__ __launch_bounds__(128) void lstm_step(const short* __restrict__ hin,  // [256][1024]
                                                 const short* __restrict__ Wstk, // [4096][1344]
                                                 const short* __restrict__ xg_t, // [256][4096]
                                                 float* __restrict__ c,          // [256][1024]
                                                 short* __restrict__ hout,
                                                 int dogemm) {
    __shared__ __attribute__((aligned(16))) short As[2][32 * 128];
    __shared__ __attribute__((aligned(16))) short Bs[2][64 * 128];
    const int tid = threadIdx.x, l = tid & 63, w = tid >> 6;
    const int hi = l >> 4, hl = l & 15;
    const int bid = blockIdx.x;             // 512
    const int xcd = bid & 7, ii = bid >> 3;
    const int ny = xcd * 8 + (ii & 7);      // n' panel [0,64)
    const int mx = ii >> 3;                 // m panel [0,8)
    const int m0 = mx * 32, n0g = ny * 64;

    f32x4 acc[4];
    for (int i = 0; i < 4; i++) acc[i] = f32x4{0.f, 0.f, 0.f, 0.f};

    if (dogemm) {
        const short* asrc[4];
        const short* bsrc[8];
        for (int i = 0; i < 4; i++) {
            int s = i * 128 + tid;
            int r = s >> 4, cs = s & 15;
            asrc[i] = hin + (size_t)(m0 + r) * 1024 + ((cs ^ (r & 15)) * 8);
        }
        for (int i = 0; i < 8; i++) {
            int s = i * 128 + tid;
            int r = s >> 4, cs = s & 15;
            bsrc[i] = Wstk + (size_t)(n0g + r) * 1344 + 320 + ((cs ^ (r & 15)) * 8);
        }
        // prologue: stage kt=0 into buf 0
        for (int i = 0; i < 4; i++) gload16(asrc[i], &As[0][(i * 128 + tid) * 8]);
        for (int i = 0; i < 8; i++) gload16(bsrc[i], &Bs[0][(i * 128 + tid) * 8]);

        for (int kt = 0; kt < 8; ++kt) {
            const int cur = kt & 1;
            if (kt < 7) {
                const int k0 = (kt + 1) * 128;
                for (int i = 0; i < 4; i++)
                    gload16(asrc[i] + k0, &As[cur ^ 1][(i * 128 + tid) * 8]);
                for (int i = 0; i < 8; i++)
                    gload16(bsrc[i] + k0, &Bs[cur ^ 1][(i * 128 + tid) * 8]);
                asm volatile("s_waitcnt vmcnt(12)" ::: "memory");
            } else {
                asm volatile("s_waitcnt vmcnt(0)" ::: "memory");
            }
            __builtin_amdgcn_sched_barrier(0);
            __builtin_amdgcn_s_barrier();
            __builtin_amdgcn_sched_barrier(0);
#pragma unroll
            for (int ks = 0; ks < 4; ++ks) {
                const int mrow = w * 16 + hl;
                const int ca = (ks * 4 + hi) ^ hl;
                short8 a = *(const short8*)&As[cur][mrow * 128 + ca * 8];
#pragma unroll
                for (int nf = 0; nf < 4; ++nf) {
                    const int nrow = nf * 16 + hl;
                    short8 b = *(const short8*)&Bs[cur][nrow * 128 + ca * 8];
                    acc[nf] = mfma16(a, b, acc[nf]);
                }
            }
            __builtin_amdgcn_sched_barrier(0);
            asm volatile("s_waitcnt lgkmcnt(0)" ::: "memory");
            __builtin_amdgcn_s_barrier();
            __builtin_amdgcn_sched_barrier(0);
        }
    }

    // epilogue: acc[gate] + xg -> cell update -> h_{t+1}
    const short* xr0 = xg_t + (size_t)(m0 + w * 16 + hi * 4) * 4096 + n0g + hl;
    for (int rg = 0; rg < 4; ++rg) {
        const short* xr = xr0 + (size_t)rg * 4096;
        float ig = acc[0][rg] + bf2f(xr[0]);
        float fg = acc[1][rg] + bf2f(xr[16]);
        float gg = acc[2][rg] + bf2f(xr[32]);
        float og = acc[3][rg] + bf2f(xr[48]);
        size_t off = (size_t)(m0 + w * 16 + hi * 4 + rg) * 1024 + ny * 16 + hl;
        float cn = sigf(fg) * c[off] + sigf(ig) * tanh_f(gg);
        c[off] = cn;
        hout[off] = f2bf(sigf(og) * tanh_f(cn));
    }
}

// ---------------- gated MLP (R3 structure: pure gload16, syncthreads) ----------------

// C[dr][1024]: A = Ac[dr][0:2048] (compacted box bf16) ‖ h[bmap[dr]] (direct).
// 128x128 tile, BK=64, 4 waves (2x2), acc 4x4. Epilogue fuses gated-MLP + f_w dot.
__global__ __launch_bounds__(256) void mlp_gemm(const short* __restrict__ Ac,   // [Mpad][2048]
                                                const short* __restrict__ hb,   // [256][1024]
                                                const short* __restrict__ Wcat, // [1024][3072]
                                                const int* __restrict__ mliveptr,
                                                const int* __restrict__ bmap,
                                                const float* __restrict__ Wb,
                                                const float* __restrict__ Wpb,
                                                const float* __restrict__ fw,
                                                float* __restrict__ logits) {
    __shared__ __attribute__((aligned(16))) short As[128 * 64];
    __shared__ __attribute__((aligned(16))) short Bs[128 * 64];
    const int Mlive = *mliveptr;
    const int tid = threadIdx.x, l = tid & 63, w = tid >> 6;
    const int bid = blockIdx.x;              // 1600
    const int xcd = bid & 7, ii = bid >> 3;  // ii in [0,200)
    const int x = ii & 7, q = ii >> 3;       // q in [0,25)
    const int y = q * 8 + xcd;
    const int n0 = x * 128, m0 = y * 128;
    if (m0 >= Mlive) return;
    const int wm = w >> 1, wn = w & 1;

    const short* asrc[4];
    const short* hsrc[4];
    const short* bsrc[4];
    for (int i = 0; i < 4; i++) {
        int r = w * 32 + i * 8 + (l >> 3);
        int cs = (l & 7) ^ (r & 7);
        asrc[i] = Ac + (size_t)(m0 + r) * 2048 + cs * 8;
        hsrc[i] = hb + (size_t)bmap[m0 + r] * 1024 + cs * 8;
        bsrc[i] = Wcat + (size_t)(n0 + r) * 3072 + cs * 8;
    }

    f32x4 acc[4][4];
    for (int i = 0; i < 4; i++)
        for (int j = 0; j < 4; j++) acc[i][j] = f32x4{0.f, 0.f, 0.f, 0.f};

    for (int kt = 0; kt < 48; ++kt) {
        const int k0 = kt * 64;
        __syncthreads();
        if (kt < 32) {
            for (int i = 0; i < 4; i++)
                gload16(asrc[i] + k0, &As[(w * 32 + i * 8) * 64]);
        } else {
            const int kq = k0 - 2048;
            for (int i = 0; i < 4; i++)
                gload16(hsrc[i] + kq, &As[(w * 32 + i * 8) * 64]);
        }
        for (int i = 0; i < 4; i++)
            gload16(bsrc[i] + k0, &Bs[(w * 32 + i * 8) * 64]);
        __syncthreads();
        for (int ks = 0; ks < 2; ++ks) {
            short8 a[4], b[4];
            for (int mf = 0; mf < 4; ++mf) {
                int m = wm * 64 + mf * 16 + (l & 15);
                int ca = (ks * 4 + (l >> 4)) ^ (m & 7);
                a[mf] = *(const short8*)&As[m * 64 + ca * 8];
            }
            for (int nf = 0; nf < 4; ++nf) {
                int n = wn * 64 + nf * 16 + (l & 15);
                int cb = (ks * 4 + (l >> 4)) ^ (n & 7);
                b[nf] = *(const short8*)&Bs[n * 64 + cb * 8];
            }
            for (int mf = 0; mf < 4; ++mf)
                for (int nf = 0; nf < 4; ++nf)
                    acc[mf][nf] = mfma16(a[mf], b[nf], acc[mf][nf]);
        }
    }

    const int hl = l & 15, hi = l >> 4;
    for (int mf = 0; mf < 4; ++mf) {
        float part[4] = {0.f, 0.f, 0.f, 0.f};
        for (int p = 0; p < 2; ++p) {
            int ntg = (n0 + wn * 64) / 16 + 2 * p;
            int hg = ntg >> 1;
            int h = hg * 16 + hl;
            float fwv = fw[h], wbv = Wb[h], wpbv = Wpb[h];
            for (int rg = 0; rg < 4; ++rg) {
                float y2 = tanh_f(acc[mf][2 * p][rg] + wbv);
                float g2 = sigf(acc[mf][2 * p + 1][rg] + wpbv);
                part[rg] += y2 * g2 * fwv;
            }
        }
        for (int rg = 0; rg < 4; ++rg) {
            float v = part[rg];
            v += __shfl_xor(v, 1, 64);
            v += __shfl_xor(v, 2, 64);
            v += __shfl_xor(v, 4, 64);
            v += __shfl_xor(v, 8, 64);
            if (hl == 0) {
                int row = m0 + wm * 64 + mf * 16 + hi * 4 + rg;
                atomicAdd(&logits[row], v);
            }
        }
    }
}

__global__ __launch_bounds__(128) void reduce_out(const float* __restrict__ logits,
                                                  const int* __restrict__ index,
                                                  const int* __restrict__ cum,
                                                  float* __restrict__ out) {
    int b = blockIdx.x, t = threadIdx.x;
    int idx = index[b];
    int base = cum[b];
    float v = 0.f;
    if (t < 100 && t < idx) v = sigf(logits[base + t]);
    for (int m = 32; m; m >>= 1) v += __shfl_down(v, m, 64);
    __shared__ float s[2];
    if ((t & 63) == 0) s[t >> 6] = v;
    __syncthreads();
    if (t == 0) out[b] = s[0] + s[1];
}

// ---------------- host ----------------

extern "C" void kernel_launch(void* const* d_in, const int* in_sizes, int n_in,
                              void* d_out, int out_size, void* d_ws, size_t ws_size,
                              hipStream_t stream) {
    (void)in_sizes; (void)n_in; (void)out_size; (void)ws_size;
    const float* box = (const float*)d_in[2];
    const float* qf  = (const float*)d_in[3];
    const int* index = (const int*)d_in[5];
    const float* Wih = (const float*)d_in[6];
    const float* Whh = (const float*)d_in[7];
    const float* bih = (const float*)d_in[8];
    const float* bhh = (const float*)d_in[9];
    const float* Ww  = (const float*)d_in[10];
    const float* Wb  = (const float*)d_in[11];
    const float* Wpw = (const float*)d_in[12];
    const float* Wpb = (const float*)d_in[13];
    const float* fw  = (const float*)d_in[14];

    char* p = (char*)d_ws;
    short* Wstk = (short*)p;  p += (size_t)4096 * 1344 * 2;
    short* Wcat = (short*)p;  p += (size_t)1024 * 3072 * 2;
    short* xb   = (short*)p;  p += (size_t)3584 * 320 * 2;
    short* hb0  = (short*)p;  p += (size_t)256 * 1024 * 2;
    short* hb1  = (short*)p;  p += (size_t)256 * 1024 * 2;
    short* xg   = (short*)p;  p += (size_t)3584 * 4096 * 2;
    float* c    = (float*)p;  p += (size_t)256 * 1024 * 4;
    int*   cum  = (int*)p;    p += 260 * 4;
    int*   rowmap = (int*)p;  p += (size_t)(25600 + 128) * 4;
    int*   bmap = (int*)p;    p += (size_t)(25600 + 128) * 4;
    float* lgt  = (float*)p;  p += (size_t)25600 * 4;
    p = (char*)(((uintptr_t)p + 255) & ~(uintptr_t)255);
    short* Ac   = (short*)p;  p += (size_t)25600 * 2048 * 2;   // ~105 MB

    hipMemsetAsync(hb0, 0, (size_t)256 * 1024 * 2, stream);
    hipMemsetAsync(c, 0, (size_t)256 * 1024 * 4, stream);
    hipMemsetAsync(lgt, 0, (size_t)25600 * 4, stream);

    prep_index<<<1, 256, 0, stream>>>(index, cum, rowmap, bmap);
    prep_wstk<<<(4096 * 1344) / 256, 256, 0, stream>>>(Wih, Whh, bih, bhh, Wstk);
    prep_x<<<(14 * 256 * 320) / 256, 256, 0, stream>>>(qf, xb);
    prep_wcat<<<(1024 * 3072) / 256, 256, 0, stream>>>(Ww, Wpw, Wcat);

    compact_box<<<25600, 256, 0, stream>>>(box, index, cum, Ac);

    xg_gemm<<<dim3(32, 28), 256, 0, stream>>>(xb, Wstk, xg);

    short* hbuf[2] = {hb0, hb1};
    for (int t = 0; t < 14; ++t) {
        lstm_step<<<512, 128, 0, stream>>>(
            hbuf[t & 1], Wstk, xg + (size_t)t * 256 * 4096, c,
            hbuf[(t & 1) ^ 1], t == 0 ? 0 : 1);
    }
    // final hidden state h_14 in hb0

    mlp_gemm<<<1600, 256, 0, stream>>>(Ac, hb0, Wcat, cum + 256, bmap,
                                       Wb, Wpb, fw, lgt);
    reduce_out<<<256, 128, 0, stream>>>(lgt, index, cum, (float*)d_out);
}

// Round 9
// 341.051 us; speedup vs baseline: 1.0686x; 1.0314x over previous
//
#include <hip/hip_runtime.h>
#include <cstdint>
#include <cstddef>

#define DEVI __device__ __forceinline__

typedef __attribute__((ext_vector_type(8))) short short8;
typedef __attribute__((ext_vector_type(4))) float f32x4;
typedef __bf16 bf16x8 __attribute__((ext_vector_type(8)));

DEVI float sigf(float x) { return 1.0f / (1.0f + __expf(-x)); }
DEVI float tanh_f(float x) { return 2.0f / (1.0f + __expf(-2.0f * x)) - 1.0f; }

DEVI short f2bf(float x) {
    uint32_t u = __builtin_bit_cast(uint32_t, x);
    u += 0x7FFFu + ((u >> 16) & 1u);   // RTNE
    return (short)(u >> 16);
}
DEVI float bf2f(short s) {
    uint32_t u = ((uint32_t)(unsigned short)s) << 16;
    return __builtin_bit_cast(float, u);
}

DEVI void gload16(const void* g, void* l) {
    __builtin_amdgcn_global_load_lds(
        (const __attribute__((address_space(1))) void*)g,
        (__attribute__((address_space(3))) void*)l, 16, 0, 0);
}

DEVI f32x4 mfma16(short8 a, short8 b, f32x4 c) {
    return __builtin_amdgcn_mfma_f32_16x16x32_bf16(
        __builtin_bit_cast(bf16x8, a), __builtin_bit_cast(bf16x8, b), c, 0, 0, 0);
}

// ---------------- fused prep: weights, x, and buffer zeroing (short8 per thread) ----

#define W_SLOTS   688128   // 4096*1344/8
#define WC_SLOTS  393216   // 1024*3072/8
#define XB_SLOTS  143360   // 3584*320/8
#define HB_SLOTS  32768    // 256*1024*2B /16
#define C_SLOTS   65536    // 256*1024*4B /16
#define LG_SLOTS  6400     // 25600*4B /16
#define PREP_TOT  (W_SLOTS + WC_SLOTS + XB_SLOTS + HB_SLOTS + C_SLOTS + LG_SLOTS)

__global__ __launch_bounds__(256) void prep_all(const float* __restrict__ Wih,
                                                const float* __restrict__ Whh,
                                                const float* __restrict__ bih,
                                                const float* __restrict__ bhh,
                                                const float* __restrict__ Ww,
                                                const float* __restrict__ Wpw,
                                                const float* __restrict__ q,
                                                short* __restrict__ Wstk,
                                                short* __restrict__ Wcat,
                                                short* __restrict__ xb,
                                                short* __restrict__ hb0,
                                                float* __restrict__ c,
                                                float* __restrict__ lgt) {
    int s = blockIdx.x * 256 + threadIdx.x;
    if (s < W_SLOTS) {
        // Wstk[n'][k], n' = hblk*64 + gate*16 + hl; k<300: W_ih, k==300: bias, [320,1344): W_hh
        int n = s / 168, c8 = s - n * 168, kb = c8 * 8;
        int hblk = n >> 6, gate = (n >> 4) & 3, hl = n & 15;
        int on = gate * 1024 + hblk * 16 + hl;
        short8 o;
#pragma unroll
        for (int e = 0; e < 8; ++e) {
            int k = kb + e;
            float v;
            if (k < 300) v = Wih[on * 300 + k];
            else if (k == 300) v = bih[on] + bhh[on];
            else if (k < 320) v = 0.f;
            else v = Whh[on * 1024 + (k - 320)];
            o[e] = f2bf(v);
        }
        *(short8*)&Wstk[n * 1344 + kb] = o;
        return;
    }
    s -= W_SLOTS;
    if (s < WC_SLOTS) {
        // Wcat[n'][k]: hg=n'>>5, which=(n'>>4)&1, h=hg*16+(n'&15)
        int n = s / 384, c8 = s - n * 384, kb = c8 * 8;
        int hg = n >> 5, which = (n >> 4) & 1, hl = n & 15;
        int h = hg * 16 + hl;
        const float* src = (which ? Wpw : Ww) + (size_t)h * 3072 + kb;
        float4 v0 = *(const float4*)src;
        float4 v1 = *(const float4*)(src + 4);
        short8 o;
        o[0] = f2bf(v0.x); o[1] = f2bf(v0.y); o[2] = f2bf(v0.z); o[3] = f2bf(v0.w);
        o[4] = f2bf(v1.x); o[5] = f2bf(v1.y); o[6] = f2bf(v1.z); o[7] = f2bf(v1.w);
        *(short8*)&Wcat[(size_t)n * 3072 + kb] = o;
        return;
    }
    s -= WC_SLOTS;
    if (s < XB_SLOTS) {
        // xb[t][b][e]: e<300 -> q[(b*14+t)*300+e], e==300 -> 1.0, else 0
        int row = s / 40, c8 = s - row * 40, eb = c8 * 8;
        int t = row / 256, b = row - t * 256;
        const float* qr = q + (size_t)(b * 14 + t) * 300;
        short8 o;
#pragma unroll
        for (int e = 0; e < 8; ++e) {
            int ee = eb + e;
            float v = (ee < 300) ? qr[ee] : (ee == 300 ? 1.0f : 0.0f);
            o[e] = f2bf(v);
        }
        *(short8*)&xb[(size_t)row * 320 + eb] = o;
        return;
    }
    s -= XB_SLOTS;
    if (s < HB_SLOTS) { ((short8*)hb0)[s] = short8{0,0,0,0,0,0,0,0}; return; }
    s -= HB_SLOTS;
    if (s < C_SLOTS) { ((f32x4*)c)[s] = f32x4{0.f,0.f,0.f,0.f}; return; }
    s -= C_SLOTS;
    if (s < LG_SLOTS) { ((f32x4*)lgt)[s] = f32x4{0.f,0.f,0.f,0.f}; return; }
}

// exclusive prefix sum of index[256] -> cum[0..256]; cum[256]=Mlive.
// bmap[dr] = sample b for dr < Mlive, +128 pad entries -> sample 0.
__global__ __launch_bounds__(256) void prep_index(const int* __restrict__ index,
                                                  int* __restrict__ cum,
                                                  int* __restrict__ bmap) {
    __shared__ int s[256];
    int t = threadIdx.x;
    int myidx = index[t];
    s[t] = myidx;
    __syncthreads();
    for (int off = 1; off < 256; off <<= 1) {
        int v = (t >= off) ? s[t - off] : 0;
        __syncthreads();
        s[t] += v;
        __syncthreads();
    }
    cum[t + 1] = s[t];
    if (t == 0) cum[0] = 0;
    int base = s[t] - myidx;
    for (int j = 0; j < myidx; ++j) bmap[base + j] = t;
    int Ml = s[255];
    if (t < 128) bmap[Ml + t] = 0;
}

// Compact live box rows into Ac[dr][2048] bf16 (box part only).
__global__ __launch_bounds__(256) void compact_box(const float* __restrict__ box,
                                                   const int* __restrict__ index,
                                                   const int* __restrict__ cum,
                                                   short* __restrict__ Ac) {
    int m = blockIdx.x;                  // 25600
    int b = m / 100, j = m - b * 100;
    if (j >= index[b]) return;
    size_t dr = (size_t)(cum[b] + j);
    int t = threadIdx.x;
    const float* src = box + (size_t)m * 2048 + t * 8;
    float4 v0 = *(const float4*)src;
    float4 v1 = *(const float4*)(src + 4);
    short8 s;
    s[0] = f2bf(v0.x); s[1] = f2bf(v0.y); s[2] = f2bf(v0.z); s[3] = f2bf(v0.w);
    s[4] = f2bf(v1.x); s[5] = f2bf(v1.y); s[6] = f2bf(v1.z); s[7] = f2bf(v1.w);
    *(short8*)&Ac[dr * 2048 + t * 8] = s;
}

// ---------------- LSTM part 1: x-projection for all timesteps ----------------

__global__ __launch_bounds__(256) void xg_gemm(const short* __restrict__ xb,   // [3584][320]
                                               const short* __restrict__ Wstk, // [4096][1344]
                                               short* __restrict__ xg) {       // [3584][4096]
    __shared__ __attribute__((aligned(16))) short As[128 * 64];
    __shared__ __attribute__((aligned(16))) short Bs[128 * 64];
    const int tid = threadIdx.x, l = tid & 63, w = tid >> 6;
    const int n0 = blockIdx.x * 128;  // 32
    const int m0 = blockIdx.y * 128;  // 28
    const int wm = w >> 1, wn = w & 1;

    const short* asrc[4];
    const short* bsrc[4];
    for (int i = 0; i < 4; i++) {
        int r = w * 32 + i * 8 + (l >> 3);
        int cs = (l & 7) ^ (r & 7);
        asrc[i] = xb + (size_t)(m0 + r) * 320 + cs * 8;
        bsrc[i] = Wstk + (size_t)(n0 + r) * 1344 + cs * 8;
    }

    f32x4 acc[4][4];
    for (int i = 0; i < 4; i++)
        for (int j = 0; j < 4; j++) acc[i][j] = f32x4{0.f, 0.f, 0.f, 0.f};

    for (int kt = 0; kt < 5; ++kt) {
        const int k0 = kt * 64;
        __syncthreads();
        for (int i = 0; i < 4; i++)
            gload16(asrc[i] + k0, &As[(w * 32 + i * 8) * 64]);
        for (int i = 0; i < 4; i++)
            gload16(bsrc[i] + k0, &Bs[(w * 32 + i * 8) * 64]);
        __syncthreads();
        for (int ks = 0; ks < 2; ++ks) {
            short8 a[4], b[4];
            for (int mf = 0; mf < 4; ++mf) {
                int m = wm * 64 + mf * 16 + (l & 15);
                int ca = (ks * 4 + (l >> 4)) ^ (m & 7);
                a[mf] = *(const short8*)&As[m * 64 + ca * 8];
            }
            for (int nf = 0; nf < 4; ++nf) {
                int n = wn * 64 + nf * 16 + (l & 15);
                int cb = (ks * 4 + (l >> 4)) ^ (n & 7);
                b[nf] = *(const short8*)&Bs[n * 64 + cb * 8];
            }
            for (int mf = 0; mf < 4; ++mf)
                for (int nf = 0; nf < 4; ++nf)
                    acc[mf][nf] = mfma16(a[mf], b[nf], acc[mf][nf]);
        }
    }
    const int hl = l & 15, hi = l >> 4;
    for (int mf = 0; mf < 4; ++mf)
        for (int nf = 0; nf < 4; ++nf)
            for (int rg = 0; rg < 4; ++rg) {
                int row = m0 + wm * 64 + mf * 16 + hi * 4 + rg;
                int col = n0 + wn * 64 + nf * 16 + hl;
                xg[(size_t)row * 4096 + col] = f2bf(acc[mf][nf][rg]);
            }
}

// ---------------- LSTM part 2: per-step recurrent GEMM, dbuf pipelined ----------------

__global__ __launch_bounds__(128) void lstm_step(const short* __restrict__ hin,  // [256][1024]
                                                 const short* __restrict__ Wstk, // [4096][1344]
                                                 const short* __restrict__ xg_t, // [256][4096]
                                                 float* __restrict__ c,          // [256][1024]
                                                 short* __restrict__ hout,
                                                 int dogemm) {
    __shared__ __attribute__((aligned(16))) short As[2][32 * 128];
    __shared__ __attribute__((aligned(16))) short Bs[2][64 * 128];
    const int tid = threadIdx.x, l = tid & 63, w = tid >> 6;
    const int hi = l >> 4, hl = l & 15;
    const int bid = blockIdx.x;             // 512
    const int xcd = bid & 7, ii = bid >> 3;
    const int ny = xcd * 8 + (ii & 7);      // n' panel [0,64)
    const int mx = ii >> 3;                 // m panel [0,8)
    const int m0 = mx * 32, n0g = ny * 64;

    f32x4 acc[4];
    for (int i = 0; i < 4; i++) acc[i] = f32x4{0.f, 0.f, 0.f, 0.f};

    if (dogemm) {
        const short* asrc[4];
        const short* bsrc[8];
        for (int i = 0; i < 4; i++) {
            int s = i * 128 + tid;
            int r = s >> 4, cs = s & 15;
            asrc[i] = hin + (size_t)(m0 + r) * 1024 + ((cs ^ (r & 15)) * 8);
        }
        for (int i = 0; i < 8; i++) {
            int s = i * 128 + tid;
            int r = s >> 4, cs = s & 15;
            bsrc[i] = Wstk + (size_t)(n0g + r) * 1344 + 320 + ((cs ^ (r & 15)) * 8);
        }
        for (int i = 0; i < 4; i++) gload16(asrc[i], &As[0][(i * 128 + tid) * 8]);
        for (int i = 0; i < 8; i++) gload16(bsrc[i], &Bs[0][(i * 128 + tid) * 8]);

        for (int kt = 0; kt < 8; ++kt) {
            const int cur = kt & 1;
            if (kt < 7) {
                const int k0 = (kt + 1) * 128;
                for (int i = 0; i < 4; i++)
                    gload16(asrc[i] + k0, &As[cur ^ 1][(i * 128 + tid) * 8]);
                for (int i = 0; i < 8; i++)
                    gload16(bsrc[i] + k0, &Bs[cur ^ 1][(i * 128 + tid) * 8]);
                asm volatile("s_waitcnt vmcnt(12)" ::: "memory");
            } else {
                asm volatile("s_waitcnt vmcnt(0)" ::: "memory");
            }
            __builtin_amdgcn_sched_barrier(0);
            __builtin_amdgcn_s_barrier();
            __builtin_amdgcn_sched_barrier(0);
#pragma unroll
            for (int ks = 0; ks < 4; ++ks) {
                const int mrow = w * 16 + hl;
                const int ca = (ks * 4 + hi) ^ hl;
                short8 a = *(const short8*)&As[cur][mrow * 128 + ca * 8];
#pragma unroll
                for (int nf = 0; nf < 4; ++nf) {
                    const int nrow = nf * 16 + hl;
                    short8 b = *(const short8*)&Bs[cur][nrow * 128 + ca * 8];
                    acc[nf] = mfma16(a, b, acc[nf]);
                }
            }
            __builtin_amdgcn_sched_barrier(0);
            asm volatile("s_waitcnt lgkmcnt(0)" ::: "memory");
            __builtin_amdgcn_s_barrier();
            __builtin_amdgcn_sched_barrier(0);
        }
    }

    const short* xr0 = xg_t + (size_t)(m0 + w * 16 + hi * 4) * 4096 + n0g + hl;
    for (int rg = 0; rg < 4; ++rg) {
        const short* xr = xr0 + (size_t)rg * 4096;
        float ig = acc[0][rg] + bf2f(xr[0]);
        float fg = acc[1][rg] + bf2f(xr[16]);
        float gg = acc[2][rg] + bf2f(xr[32]);
        float og = acc[3][rg] + bf2f(xr[48]);
        size_t off = (size_t)(m0 + w * 16 + hi * 4 + rg) * 1024 + ny * 16 + hl;
        float cn = sigf(fg) * c[off] + sigf(ig) * tanh_f(gg);
        c[off] = cn;
        hout[off] = f2bf(sigf(og) * tanh_f(cn));
    }
}

// ---------------- gated MLP: 2-phase dbuf, counted vmcnt (lstm_step pattern) --------

// C[dr][1024]: A = Ac[dr][0:2048] ‖ h[bmap[dr]]. 128x128 tile, BK=64, 4 waves.
// stage(kt+1) issued before compute(kt); vmcnt(8) keeps next loads in flight.
__global__ __launch_bounds__(256) void mlp_gemm(const short* __restrict__ Ac,   // [Mpad][2048]
                                                const short* __restrict__ hb,   // [256][1024]
                                                const short* __restrict__ Wcat, // [1024][3072]
                                                const int* __restrict__ mliveptr,
                                                const int* __restrict__ bmap,
                                                const float* __restrict__ Wb,
                                                const float* __restrict__ Wpb,
                                                const float* __restrict__ fw,
                                                float* __restrict__ logits) {
    __shared__ __attribute__((aligned(16))) short As[2][128 * 64];   // 32 KB
    __shared__ __attribute__((aligned(16))) short Bs[2][128 * 64];   // 32 KB
    const int Mlive = *mliveptr;
    const int tid = threadIdx.x, l = tid & 63, w = tid >> 6;
    const int bid = blockIdx.x;              // 1600
    const int xcd = bid & 7, ii = bid >> 3;  // ii in [0,200)
    const int x = ii & 7, q = ii >> 3;       // q in [0,25)
    const int y = q * 8 + xcd;
    const int n0 = x * 128, m0 = y * 128;
    if (m0 >= Mlive) return;
    const int wm = w >> 1, wn = w & 1;

    const short* asrc[4];
    const short* hsrc[4];
    const short* bsrc[4];
    int ldso[4];
    for (int i = 0; i < 4; i++) {
        int r = w * 32 + i * 8 + (l >> 3);
        int cs = (l & 7) ^ (r & 7);
        asrc[i] = Ac + (size_t)(m0 + r) * 2048 + cs * 8;
        hsrc[i] = hb + (size_t)bmap[m0 + r] * 1024 + cs * 8;
        bsrc[i] = Wcat + (size_t)(n0 + r) * 3072 + cs * 8;
        ldso[i] = (w * 32 + i * 8) * 64;
    }

    f32x4 acc[4][4];
    for (int i = 0; i < 4; i++)
        for (int j = 0; j < 4; j++) acc[i][j] = f32x4{0.f, 0.f, 0.f, 0.f};

    // prologue: stage kt=0 into buf0
    for (int i = 0; i < 4; i++) gload16(asrc[i], &As[0][ldso[i]]);
    for (int i = 0; i < 4; i++) gload16(bsrc[i], &Bs[0][ldso[i]]);

    for (int kt = 0; kt < 48; ++kt) {
        const int cur = kt & 1;
        if (kt < 47) {
            const int k1 = (kt + 1) * 64;
            if (kt + 1 < 32) {
                for (int i = 0; i < 4; i++)
                    gload16(asrc[i] + k1, &As[cur ^ 1][ldso[i]]);
            } else {
                const int kq = k1 - 2048;
                for (int i = 0; i < 4; i++)
                    gload16(hsrc[i] + kq, &As[cur ^ 1][ldso[i]]);
            }
            for (int i = 0; i < 4; i++)
                gload16(bsrc[i] + k1, &Bs[cur ^ 1][ldso[i]]);
            asm volatile("s_waitcnt vmcnt(8)" ::: "memory");
        } else {
            asm volatile("s_waitcnt vmcnt(0)" ::: "memory");
        }
        __builtin_amdgcn_sched_barrier(0);
        __builtin_amdgcn_s_barrier();
        __builtin_amdgcn_sched_barrier(0);
        for (int ks = 0; ks < 2; ++ks) {
            short8 a[4], b[4];
            for (int mf = 0; mf < 4; ++mf) {
                int m = wm * 64 + mf * 16 + (l & 15);
                int ca = (ks * 4 + (l >> 4)) ^ (m & 7);
                a[mf] = *(const short8*)&As[cur][m * 64 + ca * 8];
            }
            for (int nf = 0; nf < 4; ++nf) {
                int n = wn * 64 + nf * 16 + (l & 15);
                int cb = (ks * 4 + (l >> 4)) ^ (n & 7);
                b[nf] = *(const short8*)&Bs[cur][n * 64 + cb * 8];
            }
            for (int mf = 0; mf < 4; ++mf)
                for (int nf = 0; nf < 4; ++nf)
                    acc[mf][nf] = mfma16(a[mf], b[nf], acc[mf][nf]);
        }
        __builtin_amdgcn_sched_barrier(0);
        asm volatile("s_waitcnt lgkmcnt(0)" ::: "memory");
        __builtin_amdgcn_s_barrier();
        __builtin_amdgcn_sched_barrier(0);
    }

    const int hl = l & 15, hi = l >> 4;
    for (int mf = 0; mf < 4; ++mf) {
        float part[4] = {0.f, 0.f, 0.f, 0.f};
        for (int p = 0; p < 2; ++p) {
            int ntg = (n0 + wn * 64) / 16 + 2 * p;
            int hg = ntg >> 1;
            int h = hg * 16 + hl;
            float fwv = fw[h], wbv = Wb[h], wpbv = Wpb[h];
            for (int rg = 0; rg < 4; ++rg) {
                float y2 = tanh_f(acc[mf][2 * p][rg] + wbv);
                float g2 = sigf(acc[mf][2 * p + 1][rg] + wpbv);
                part[rg] += y2 * g2 * fwv;
            }
        }
        for (int rg = 0; rg < 4; ++rg) {
            float v = part[rg];
            v += __shfl_xor(v, 1, 64);
            v += __shfl_xor(v, 2, 64);
            v += __shfl_xor(v, 4, 64);
            v += __shfl_xor(v, 8, 64);
            if (hl == 0) {
                int row = m0 + wm * 64 + mf * 16 + hi * 4 + rg;
                atomicAdd(&logits[row], v);
            }
        }
    }
}

__global__ __launch_bounds__(128) void reduce_out(const float* __restrict__ logits,
                                                  const int* __restrict__ index,
                                                  const int* __restrict__ cum,
                                                  float* __restrict__ out) {
    int b = blockIdx.x, t = threadIdx.x;
    int idx = index[b];
    int base = cum[b];
    float v = 0.f;
    if (t < 100 && t < idx) v = sigf(logits[base + t]);
    for (int m = 32; m; m >>= 1) v += __shfl_down(v, m, 64);
    __shared__ float s[2];
    if ((t & 63) == 0) s[t >> 6] = v;
    __syncthreads();
    if (t == 0) out[b] = s[0] + s[1];
}

// ---------------- host ----------------

extern "C" void kernel_launch(void* const* d_in, const int* in_sizes, int n_in,
                              void* d_out, int out_size, void* d_ws, size_t ws_size,
                              hipStream_t stream) {
    (void)in_sizes; (void)n_in; (void)out_size; (void)ws_size;
    const float* box = (const float*)d_in[2];
    const float* qf  = (const float*)d_in[3];
    const int* index = (const int*)d_in[5];
    const float* Wih = (const float*)d_in[6];
    const float* Whh = (const float*)d_in[7];
    const float* bih = (const float*)d_in[8];
    const float* bhh = (const float*)d_in[9];
    const float* Ww  = (const float*)d_in[10];
    const float* Wb  = (const float*)d_in[11];
    const float* Wpw = (const float*)d_in[12];
    const float* Wpb = (const float*)d_in[13];
    const float* fw  = (const float*)d_in[14];

    char* p = (char*)d_ws;
    short* Wstk = (short*)p;  p += (size_t)4096 * 1344 * 2;
    short* Wcat = (short*)p;  p += (size_t)1024 * 3072 * 2;
    short* xb   = (short*)p;  p += (size_t)3584 * 320 * 2;
    short* hb0  = (short*)p;  p += (size_t)256 * 1024 * 2;
    short* hb1  = (short*)p;  p += (size_t)256 * 1024 * 2;
    short* xg   = (short*)p;  p += (size_t)3584 * 4096 * 2;
    float* c    = (float*)p;  p += (size_t)256 * 1024 * 4;
    int*   cum  = (int*)p;    p += 260 * 4;
    int*   bmap = (int*)p;    p += (size_t)(25600 + 128) * 4;
    float* lgt  = (float*)p;  p += (size_t)25600 * 4;
    p = (char*)(((uintptr_t)p + 255) & ~(uintptr_t)255);
    short* Ac   = (short*)p;  p += (size_t)25600 * 2048 * 2;   // ~105 MB

    prep_index<<<1, 256, 0, stream>>>(index, cum, bmap);
    prep_all<<<(PREP_TOT + 255) / 256, 256, 0, stream>>>(
        Wih, Whh, bih, bhh, Ww, Wpw, qf, Wstk, Wcat, xb, hb0, c, lgt);

    compact_box<<<25600, 256, 0, stream>>>(box, index, cum, Ac);

    xg_gemm<<<dim3(32, 28), 256, 0, stream>>>(xb, Wstk, xg);

    short* hbuf[2] = {hb0, hb1};
    for (int t = 0; t < 14; ++t) {
        lstm_step<<<512, 128, 0, stream>>>(
            hbuf[t & 1], Wstk, xg + (size_t)t * 256 * 4096, c,
            hbuf[(t & 1) ^ 1], t == 0 ? 0 : 1);
    }
    // final hidden state h_14 in hb0

    mlp_gemm<<<1600, 256, 0, stream>>>(Ac, hb0, Wcat, cum + 256, bmap,
                                       Wb, Wpb, fw, lgt);
    reduce_out<<<256, 128, 0, stream>>>(lgt, index, cum, (float*)d_out);
}

// Round 10
// 299.005 us; speedup vs baseline: 1.2189x; 1.1406x over previous
//
#include <hip/hip_runtime.h>
#include <cstdint>
#include <cstddef>

#define DEVI __device__ __forceinline__

typedef __attribute__((ext_vector_type(8))) short short8;
typedef __attribute__((ext_vector_type(4))) float f32x4;
typedef __bf16 bf16x8 __attribute__((ext_vector_type(8)));

DEVI float sigf(float x) { return 1.0f / (1.0f + __expf(-x)); }
DEVI float tanh_f(float x) { return 2.0f / (1.0f + __expf(-2.0f * x)) - 1.0f; }

DEVI short f2bf(float x) {
    uint32_t u = __builtin_bit_cast(uint32_t, x);
    u += 0x7FFFu + ((u >> 16) & 1u);   // RTNE
    return (short)(u >> 16);
}
DEVI float bf2f(short s) {
    uint32_t u = ((uint32_t)(unsigned short)s) << 16;
    return __builtin_bit_cast(float, u);
}

DEVI void gload16(const void* g, void* l) {
    __builtin_amdgcn_global_load_lds(
        (const __attribute__((address_space(1))) void*)g,
        (__attribute__((address_space(3))) void*)l, 16, 0, 0);
}

DEVI f32x4 mfma16(short8 a, short8 b, f32x4 c) {
    return __builtin_amdgcn_mfma_f32_16x16x32_bf16(
        __builtin_bit_cast(bf16x8, a), __builtin_bit_cast(bf16x8, b), c, 0, 0, 0);
}

// ---------------- fused prep: index scan + weights + x + logits zero ----------------
// block 0: prefix-scan of index -> cum, bmap (+256 pad). blocks 1..: short8 slots.

#define W_SLOTS   688128   // 4096*1344/8
#define WC_SLOTS  393216   // 1024*3072/8
#define XB_SLOTS  143360   // 3584*320/8
#define LG_SLOTS  6400     // 25600*4B /16
#define PREP_TOT  (W_SLOTS + WC_SLOTS + XB_SLOTS + LG_SLOTS)   // 1231104 = 4809*256

__global__ __launch_bounds__(256) void prep_all(const int* __restrict__ index,
                                                const float* __restrict__ Wih,
                                                const float* __restrict__ Whh,
                                                const float* __restrict__ bih,
                                                const float* __restrict__ bhh,
                                                const float* __restrict__ Ww,
                                                const float* __restrict__ Wpw,
                                                const float* __restrict__ q,
                                                int* __restrict__ cum,
                                                int* __restrict__ bmap,
                                                short* __restrict__ Wstk,
                                                short* __restrict__ Wcat,
                                                short* __restrict__ xb,
                                                float* __restrict__ lgt) {
    __shared__ int sh[256];
    if (blockIdx.x == 0) {
        int t = threadIdx.x;
        int myidx = index[t];
        sh[t] = myidx;
        __syncthreads();
        for (int off = 1; off < 256; off <<= 1) {
            int v = (t >= off) ? sh[t - off] : 0;
            __syncthreads();
            sh[t] += v;
            __syncthreads();
        }
        cum[t + 1] = sh[t];
        if (t == 0) cum[0] = 0;
        int base = sh[t] - myidx;
        for (int j = 0; j < myidx; ++j) bmap[base + j] = t;
        bmap[sh[255] + t] = 0;    // 256 pad entries
        return;
    }
    int s = (blockIdx.x - 1) * 256 + threadIdx.x;
    if (s < W_SLOTS) {
        // Wstk[n'][k], n' = hblk*64 + gate*16 + hl; k<300: W_ih, k==300: bias, [320,1344): W_hh
        int n = s / 168, c8 = s - n * 168, kb = c8 * 8;
        int hblk = n >> 6, gate = (n >> 4) & 3, hl = n & 15;
        int on = gate * 1024 + hblk * 16 + hl;
        short8 o;
#pragma unroll
        for (int e = 0; e < 8; ++e) {
            int k = kb + e;
            float v;
            if (k < 300) v = Wih[on * 300 + k];
            else if (k == 300) v = bih[on] + bhh[on];
            else if (k < 320) v = 0.f;
            else v = Whh[on * 1024 + (k - 320)];
            o[e] = f2bf(v);
        }
        *(short8*)&Wstk[n * 1344 + kb] = o;
        return;
    }
    s -= W_SLOTS;
    if (s < WC_SLOTS) {
        int n = s / 384, c8 = s - n * 384, kb = c8 * 8;
        int hg = n >> 5, which = (n >> 4) & 1, hl = n & 15;
        int h = hg * 16 + hl;
        const float* src = (which ? Wpw : Ww) + (size_t)h * 3072 + kb;
        float4 v0 = *(const float4*)src;
        float4 v1 = *(const float4*)(src + 4);
        short8 o;
        o[0] = f2bf(v0.x); o[1] = f2bf(v0.y); o[2] = f2bf(v0.z); o[3] = f2bf(v0.w);
        o[4] = f2bf(v1.x); o[5] = f2bf(v1.y); o[6] = f2bf(v1.z); o[7] = f2bf(v1.w);
        *(short8*)&Wcat[(size_t)n * 3072 + kb] = o;
        return;
    }
    s -= WC_SLOTS;
    if (s < XB_SLOTS) {
        int row = s / 40, c8 = s - row * 40, eb = c8 * 8;
        int t = row / 256, b = row - t * 256;
        const float* qr = q + (size_t)(b * 14 + t) * 300;
        short8 o;
#pragma unroll
        for (int e = 0; e < 8; ++e) {
            int ee = eb + e;
            float v = (ee < 300) ? qr[ee] : (ee == 300 ? 1.0f : 0.0f);
            o[e] = f2bf(v);
        }
        *(short8*)&xb[(size_t)row * 320 + eb] = o;
        return;
    }
    s -= XB_SLOTS;
    if (s < LG_SLOTS) { ((f32x4*)lgt)[s] = f32x4{0.f, 0.f, 0.f, 0.f}; return; }
}

// Compact live box rows into Ac[dr][2048] bf16.
__global__ __launch_bounds__(256) void compact_box(const float* __restrict__ box,
                                                   const int* __restrict__ index,
                                                   const int* __restrict__ cum,
                                                   short* __restrict__ Ac) {
    int m = blockIdx.x;                  // 25600
    int b = m / 100, j = m - b * 100;
    if (j >= index[b]) return;
    size_t dr = (size_t)(cum[b] + j);
    int t = threadIdx.x;
    const float* src = box + (size_t)m * 2048 + t * 8;
    float4 v0 = *(const float4*)src;
    float4 v1 = *(const float4*)(src + 4);
    short8 s;
    s[0] = f2bf(v0.x); s[1] = f2bf(v0.y); s[2] = f2bf(v0.z); s[3] = f2bf(v0.w);
    s[4] = f2bf(v1.x); s[5] = f2bf(v1.y); s[6] = f2bf(v1.z); s[7] = f2bf(v1.w);
    *(short8*)&Ac[dr * 2048 + t * 8] = s;
}

// ---------------- LSTM part 1: x-projection for all t + fused t=0 cell ----------------

// xg[t*256+b][n'] = xb @ Wstk(:,0:320)^T. For rows < 256 (t=0), compute
// c1 = sig(i)*tanh(g), h1 = sig(o)*tanh(c1) directly (h0=c0=0) and write c/hb1
// instead of xg (those xg rows are never read).
__global__ __launch_bounds__(256) void xg_gemm(const short* __restrict__ xb,   // [3584][320]
                                               const short* __restrict__ Wstk, // [4096][1344]
                                               short* __restrict__ xg,         // [3584][4096]
                                               float* __restrict__ c,          // [256][1024]
                                               short* __restrict__ hb1) {      // [256][1024]
    __shared__ __attribute__((aligned(16))) short As[128 * 64];
    __shared__ __attribute__((aligned(16))) short Bs[128 * 64];
    const int tid = threadIdx.x, l = tid & 63, w = tid >> 6;
    const int n0 = blockIdx.x * 128;  // 32
    const int m0 = blockIdx.y * 128;  // 28
    const int wm = w >> 1, wn = w & 1;

    const short* asrc[4];
    const short* bsrc[4];
    for (int i = 0; i < 4; i++) {
        int r = w * 32 + i * 8 + (l >> 3);
        int cs = (l & 7) ^ (r & 7);
        asrc[i] = xb + (size_t)(m0 + r) * 320 + cs * 8;
        bsrc[i] = Wstk + (size_t)(n0 + r) * 1344 + cs * 8;
    }

    f32x4 acc[4][4];
    for (int i = 0; i < 4; i++)
        for (int j = 0; j < 4; j++) acc[i][j] = f32x4{0.f, 0.f, 0.f, 0.f};

    for (int kt = 0; kt < 5; ++kt) {
        const int k0 = kt * 64;
        __syncthreads();
        for (int i = 0; i < 4; i++)
            gload16(asrc[i] + k0, &As[(w * 32 + i * 8) * 64]);
        for (int i = 0; i < 4; i++)
            gload16(bsrc[i] + k0, &Bs[(w * 32 + i * 8) * 64]);
        __syncthreads();
        for (int ks = 0; ks < 2; ++ks) {
            short8 a[4], b[4];
            for (int mf = 0; mf < 4; ++mf) {
                int m = wm * 64 + mf * 16 + (l & 15);
                int ca = (ks * 4 + (l >> 4)) ^ (m & 7);
                a[mf] = *(const short8*)&As[m * 64 + ca * 8];
            }
            for (int nf = 0; nf < 4; ++nf) {
                int n = wn * 64 + nf * 16 + (l & 15);
                int cb = (ks * 4 + (l >> 4)) ^ (n & 7);
                b[nf] = *(const short8*)&Bs[n * 64 + cb * 8];
            }
            for (int mf = 0; mf < 4; ++mf)
                for (int nf = 0; nf < 4; ++nf)
                    acc[mf][nf] = mfma16(a[mf], b[nf], acc[mf][nf]);
        }
    }
    const int hl = l & 15, hi = l >> 4;
    if (m0 < 256) {
        // t=0 fused cell update; wave's 64-col group = one hblk; nf = gate
        const int h = ((n0 + wn * 64) >> 6) * 16 + hl;
        for (int mf = 0; mf < 4; ++mf)
            for (int rg = 0; rg < 4; ++rg) {
                int b = m0 + wm * 64 + mf * 16 + hi * 4 + rg;   // sample
                float ig = acc[mf][0][rg];
                float gg = acc[mf][2][rg];
                float og = acc[mf][3][rg];
                float cn = sigf(ig) * tanh_f(gg);
                size_t off = (size_t)b * 1024 + h;
                c[off] = cn;
                hb1[off] = f2bf(sigf(og) * tanh_f(cn));
            }
    } else {
        for (int mf = 0; mf < 4; ++mf)
            for (int nf = 0; nf < 4; ++nf)
                for (int rg = 0; rg < 4; ++rg) {
                    int row = m0 + wm * 64 + mf * 16 + hi * 4 + rg;
                    int col = n0 + wn * 64 + nf * 16 + hl;
                    xg[(size_t)row * 4096 + col] = f2bf(acc[mf][nf][rg]);
                }
    }
}

// ---------------- LSTM part 2: per-step recurrent GEMM, dbuf pipelined ----------------

__global__ __launch_bounds__(128) void lstm_step(const short* __restrict__ hin,  // [256][1024]
                                                 const short* __restrict__ Wstk, // [4096][1344]
                                                 const short* __restrict__ xg_t, // [256][4096]
                                                 float* __restrict__ c,          // [256][1024]
                                                 short* __restrict__ hout) {
    __shared__ __attribute__((aligned(16))) short As[2][32 * 128];
    __shared__ __attribute__((aligned(16))) short Bs[2][64 * 128];
    const int tid = threadIdx.x, l = tid & 63, w = tid >> 6;
    const int hi = l >> 4, hl = l & 15;
    const int bid = blockIdx.x;             // 512
    const int xcd = bid & 7, ii = bid >> 3;
    const int ny = xcd * 8 + (ii & 7);      // n' panel [0,64)
    const int mx = ii >> 3;                 // m panel [0,8)
    const int m0 = mx * 32, n0g = ny * 64;

    f32x4 acc[4];
    for (int i = 0; i < 4; i++) acc[i] = f32x4{0.f, 0.f, 0.f, 0.f};

    const short* asrc[4];
    const short* bsrc[8];
    for (int i = 0; i < 4; i++) {
        int s = i * 128 + tid;
        int r = s >> 4, cs = s & 15;
        asrc[i] = hin + (size_t)(m0 + r) * 1024 + ((cs ^ (r & 15)) * 8);
    }
    for (int i = 0; i < 8; i++) {
        int s = i * 128 + tid;
        int r = s >> 4, cs = s & 15;
        bsrc[i] = Wstk + (size_t)(n0g + r) * 1344 + 320 + ((cs ^ (r & 15)) * 8);
    }
    for (int i = 0; i < 4; i++) gload16(asrc[i], &As[0][(i * 128 + tid) * 8]);
    for (int i = 0; i < 8; i++) gload16(bsrc[i], &Bs[0][(i * 128 + tid) * 8]);

    for (int kt = 0; kt < 8; ++kt) {
        const int cur = kt & 1;
        if (kt < 7) {
            const int k0 = (kt + 1) * 128;
            for (int i = 0; i < 4; i++)
                gload16(asrc[i] + k0, &As[cur ^ 1][(i * 128 + tid) * 8]);
            for (int i = 0; i < 8; i++)
                gload16(bsrc[i] + k0, &Bs[cur ^ 1][(i * 128 + tid) * 8]);
            asm volatile("s_waitcnt vmcnt(12)" ::: "memory");
        } else {
            asm volatile("s_waitcnt vmcnt(0)" ::: "memory");
        }
        __builtin_amdgcn_sched_barrier(0);
        __builtin_amdgcn_s_barrier();
        __builtin_amdgcn_sched_barrier(0);
#pragma unroll
        for (int ks = 0; ks < 4; ++ks) {
            const int mrow = w * 16 + hl;
            const int ca = (ks * 4 + hi) ^ hl;
            short8 a = *(const short8*)&As[cur][mrow * 128 + ca * 8];
#pragma unroll
            for (int nf = 0; nf < 4; ++nf) {
                const int nrow = nf * 16 + hl;
                short8 b = *(const short8*)&Bs[cur][nrow * 128 + ca * 8];
                acc[nf] = mfma16(a, b, acc[nf]);
            }
        }
        __builtin_amdgcn_sched_barrier(0);
        asm volatile("s_waitcnt lgkmcnt(0)" ::: "memory");
        __builtin_amdgcn_s_barrier();
        __builtin_amdgcn_sched_barrier(0);
    }

    const short* xr0 = xg_t + (size_t)(m0 + w * 16 + hi * 4) * 4096 + n0g + hl;
    for (int rg = 0; rg < 4; ++rg) {
        const short* xr = xr0 + (size_t)rg * 4096;
        float ig = acc[0][rg] + bf2f(xr[0]);
        float fg = acc[1][rg] + bf2f(xr[16]);
        float gg = acc[2][rg] + bf2f(xr[32]);
        float og = acc[3][rg] + bf2f(xr[48]);
        size_t off = (size_t)(m0 + w * 16 + hi * 4 + rg) * 1024 + ny * 16 + hl;
        float cn = sigf(fg) * c[off] + sigf(ig) * tanh_f(gg);
        c[off] = cn;
        hout[off] = f2bf(sigf(og) * tanh_f(cn));
    }
}

// ---------------- gated MLP: BM=256 x BN=128, 8 waves, single-buffer ----------------

// C[dr][1024]: A = Ac[dr][0:2048] ‖ h[bmap[dr]]. Halves Wcat L3 re-reads vs BM=128.
__global__ __launch_bounds__(512) void mlp_gemm(const short* __restrict__ Ac,   // [25600][2048]
                                                const short* __restrict__ hb,   // [256][1024]
                                                const short* __restrict__ Wcat, // [1024][3072]
                                                const int* __restrict__ mliveptr,
                                                const int* __restrict__ bmap,
                                                const float* __restrict__ Wb,
                                                const float* __restrict__ Wpb,
                                                const float* __restrict__ fw,
                                                float* __restrict__ logits) {
    __shared__ __attribute__((aligned(16))) short As[256 * 64];   // 32 KB
    __shared__ __attribute__((aligned(16))) short Bs[128 * 64];   // 16 KB
    const int Mlive = *mliveptr;
    const int tid = threadIdx.x, l = tid & 63, w = tid >> 6;      // w 0..7
    const int bid = blockIdx.x;              // 800
    const int xcd = bid & 7, ii = bid >> 3;  // ii 0..99
    const int x = ii & 7, q = ii >> 3;       // q 0..12
    const int y = q * 8 + xcd;
    const int n0 = x * 128, m0 = y * 256;
    if (m0 >= Mlive) return;
    const int wm = w >> 1, wn = w & 1;

    const short* asrc[4];
    const short* hsrc[4];
    int adst[4];
    const short* bsrc[2];
    int bdst[2];
    for (int i = 0; i < 4; i++) {
        int r = i * 64 + w * 8 + (l >> 3);           // 0..255
        int cs = (l & 7) ^ (r & 7);
        asrc[i] = Ac + (size_t)(m0 + r) * 2048 + cs * 8;
        hsrc[i] = hb + (size_t)bmap[m0 + r] * 1024 + cs * 8;
        adst[i] = (i * 64 + w * 8) * 64;
    }
    for (int i = 0; i < 2; i++) {
        int r = i * 64 + w * 8 + (l >> 3);           // 0..127
        int cs = (l & 7) ^ (r & 7);
        bsrc[i] = Wcat + (size_t)(n0 + r) * 3072 + cs * 8;
        bdst[i] = (i * 64 + w * 8) * 64;
    }

    f32x4 acc[4][4];
    for (int i = 0; i < 4; i++)
        for (int j = 0; j < 4; j++) acc[i][j] = f32x4{0.f, 0.f, 0.f, 0.f};

    for (int kt = 0; kt < 48; ++kt) {
        const int k0 = kt * 64;
        __syncthreads();
        if (kt < 32) {
            for (int i = 0; i < 4; i++)
                gload16(asrc[i] + k0, &As[adst[i]]);
        } else {
            const int kq = k0 - 2048;
            for (int i = 0; i < 4; i++)
                gload16(hsrc[i] + kq, &As[adst[i]]);
        }
        for (int i = 0; i < 2; i++)
            gload16(bsrc[i] + k0, &Bs[bdst[i]]);
        __syncthreads();
        for (int ks = 0; ks < 2; ++ks) {
            short8 a[4], b[4];
            for (int mf = 0; mf < 4; ++mf) {
                int m = wm * 64 + mf * 16 + (l & 15);   // 0..255
                int ca = (ks * 4 + (l >> 4)) ^ (m & 7);
                a[mf] = *(const short8*)&As[m * 64 + ca * 8];
            }
            for (int nf = 0; nf < 4; ++nf) {
                int n = wn * 64 + nf * 16 + (l & 15);   // 0..127
                int cb = (ks * 4 + (l >> 4)) ^ (n & 7);
                b[nf] = *(const short8*)&Bs[n * 64 + cb * 8];
            }
            for (int mf = 0; mf < 4; ++mf)
                for (int nf = 0; nf < 4; ++nf)
                    acc[mf][nf] = mfma16(a[mf], b[nf], acc[mf][nf]);
        }
    }

    const int hl = l & 15, hi = l >> 4;
    for (int mf = 0; mf < 4; ++mf) {
        float part[4] = {0.f, 0.f, 0.f, 0.f};
        for (int p = 0; p < 2; ++p) {
            int ntg = (n0 + wn * 64) / 16 + 2 * p;
            int hg = ntg >> 1;
            int h = hg * 16 + hl;
            float fwv = fw[h], wbv = Wb[h], wpbv = Wpb[h];
            for (int rg = 0; rg < 4; ++rg) {
                float y2 = tanh_f(acc[mf][2 * p][rg] + wbv);
                float g2 = sigf(acc[mf][2 * p + 1][rg] + wpbv);
                part[rg] += y2 * g2 * fwv;
            }
        }
        for (int rg = 0; rg < 4; ++rg) {
            float v = part[rg];
            v += __shfl_xor(v, 1, 64);
            v += __shfl_xor(v, 2, 64);
            v += __shfl_xor(v, 4, 64);
            v += __shfl_xor(v, 8, 64);
            if (hl == 0) {
                int row = m0 + wm * 64 + mf * 16 + hi * 4 + rg;
                atomicAdd(&logits[row], v);
            }
        }
    }
}

__global__ __launch_bounds__(128) void reduce_out(const float* __restrict__ logits,
                                                  const int* __restrict__ index,
                                                  const int* __restrict__ cum,
                                                  float* __restrict__ out) {
    int b = blockIdx.x, t = threadIdx.x;
    int idx = index[b];
    int base = cum[b];
    float v = 0.f;
    if (t < 100 && t < idx) v = sigf(logits[base + t]);
    for (int m = 32; m; m >>= 1) v += __shfl_down(v, m, 64);
    __shared__ float s[2];
    if ((t & 63) == 0) s[t >> 6] = v;
    __syncthreads();
    if (t == 0) out[b] = s[0] + s[1];
}

// ---------------- host ----------------

extern "C" void kernel_launch(void* const* d_in, const int* in_sizes, int n_in,
                              void* d_out, int out_size, void* d_ws, size_t ws_size,
                              hipStream_t stream) {
    (void)in_sizes; (void)n_in; (void)out_size; (void)ws_size;
    const float* box = (const float*)d_in[2];
    const float* qf  = (const float*)d_in[3];
    const int* index = (const int*)d_in[5];
    const float* Wih = (const float*)d_in[6];
    const float* Whh = (const float*)d_in[7];
    const float* bih = (const float*)d_in[8];
    const float* bhh = (const float*)d_in[9];
    const float* Ww  = (const float*)d_in[10];
    const float* Wb  = (const float*)d_in[11];
    const float* Wpw = (const float*)d_in[12];
    const float* Wpb = (const float*)d_in[13];
    const float* fw  = (const float*)d_in[14];

    char* p = (char*)d_ws;
    short* Wstk = (short*)p;  p += (size_t)4096 * 1344 * 2;
    short* Wcat = (short*)p;  p += (size_t)1024 * 3072 * 2;
    short* xb   = (short*)p;  p += (size_t)3584 * 320 * 2;
    short* hb0  = (short*)p;  p += (size_t)256 * 1024 * 2;
    short* hb1  = (short*)p;  p += (size_t)256 * 1024 * 2;
    short* xg   = (short*)p;  p += (size_t)3584 * 4096 * 2;
    float* c    = (float*)p;  p += (size_t)256 * 1024 * 4;
    int*   cum  = (int*)p;    p += 260 * 4;
    int*   bmap = (int*)p;    p += (size_t)(25600 + 256) * 4;
    float* lgt  = (float*)p;  p += (size_t)25600 * 4;
    p = (char*)(((uintptr_t)p + 255) & ~(uintptr_t)255);
    short* Ac   = (short*)p;  p += (size_t)25600 * 2048 * 2;   // ~105 MB

    prep_all<<<1 + PREP_TOT / 256, 256, 0, stream>>>(
        index, Wih, Whh, bih, bhh, Ww, Wpw, qf, cum, bmap, Wstk, Wcat, xb, lgt);

    compact_box<<<25600, 256, 0, stream>>>(box, index, cum, Ac);

    // xg + fused t=0 cell update (writes c and hb1)
    xg_gemm<<<dim3(32, 28), 256, 0, stream>>>(xb, Wstk, xg, c, hb1);

    short* hbuf[2] = {hb0, hb1};
    for (int t = 1; t < 14; ++t) {
        lstm_step<<<512, 128, 0, stream>>>(
            hbuf[t & 1], Wstk, xg + (size_t)t * 256 * 4096, c, hbuf[(t & 1) ^ 1]);
    }
    // t=13 reads hb1, writes hb0 -> final hidden state h_14 in hb0

    mlp_gemm<<<800, 512, 0, stream>>>(Ac, hb0, Wcat, cum + 256, bmap,
                                      Wb, Wpb, fw, lgt);
    reduce_out<<<256, 128, 0, stream>>>(lgt, index, cum, (float*)d_out);
}